// Round 2
// baseline (765.513 us; speedup 1.0000x reference)
//
#include <hip/hip_runtime.h>
#include <cmath>

#define T_TOK 2048
#define D_EMB 768
#define H_FFN 1536
#define NE    16
#define NPAIR (T_TOK * 4)
#define MT    64
#define NCH   64
#define KCH   128
#define NSPLIT 6

typedef __attribute__((ext_vector_type(8))) short          short8;
typedef __attribute__((ext_vector_type(8))) unsigned short ushort8;
typedef __attribute__((ext_vector_type(4))) float          floatx4;

__device__ __forceinline__ float bf2f(unsigned short u) {
  union { unsigned int i; float f; } v; v.i = ((unsigned int)u) << 16; return v.f;
}
__device__ __forceinline__ unsigned short f2bf(float f) {
  union { float f; unsigned int i; } v; v.f = f;
  unsigned int r = v.i + 0x7fffu + ((v.i >> 16) & 1u);   // RNE
  return (unsigned short)(r >> 16);
}

// ---------------- K0: dtype sniff -------------------------------------------
// bf16 data: low u16 of each u32 word is a bf16 ~N(0,1): bits14:7 (exp) in
// [100,140] essentially always. f32 data: low u16 is mantissa bits -> exp
// field ~uniform -> ~16% in range. 512 samples, threshold 300 (>25 sigma).
__global__ __launch_bounds__(64) void sniff_kernel(
    const unsigned int* __restrict__ x, int* __restrict__ flag)
{
  int lane = threadIdx.x;
  int c = 0;
  for (int i = 0; i < 8; i++) {
    unsigned int w = x[i * 64 + lane];
    unsigned int e = (w >> 7) & 0xFFu;
    c += (e >= 100u && e <= 140u) ? 1 : 0;
  }
  for (int off = 32; off > 0; off >>= 1) c += __shfl_down(c, off);
  if (lane == 0) *flag = (c > 300) ? 1 : 0;   // 1 = inputs are bf16
}

// ---------------- K0b: f32 -> bf16 canonicalization (no-op when bf16) -------
struct ConvArgs { const float* src[9]; unsigned short* dst[9]; int n[9]; };
__global__ __launch_bounds__(256) void conv_kernel(
    ConvArgs a, const int* __restrict__ flag, int total)
{
  if (*flag) return;                           // already bf16
  int stride = gridDim.x * blockDim.x;
  for (int g = blockIdx.x * blockDim.x + threadIdx.x; g < total; g += stride) {
    int off = g, s = 0;
    while (off >= a.n[s]) { off -= a.n[s]; s++; }
    a.dst[s][off] = f2bf(a.src[s][off]);
  }
}

// ---------------- K1: gating (scores -> softmax -> top3 -> expert lists) ----
// Reads ORIGINAL precision (f32 when flag==0) so top-k selection matches np.
__global__ __launch_bounds__(64) void gate_kernel(
    const unsigned short* __restrict__ x16, const float* __restrict__ x32,
    const unsigned short* __restrict__ gw16, const float* __restrict__ gw32,
    const unsigned short* __restrict__ gb16, const float* __restrict__ gb32,
    const int* __restrict__ flag,
    int* __restrict__ cnt, int* __restrict__ plist,
    int* __restrict__ psel, float* __restrict__ pw)
{
  int t = blockIdx.x;
  int lane = threadIdx.x;
  int isbf = *flag;
  float acc[NE];
#pragma unroll
  for (int e = 0; e < NE; e++) acc[e] = 0.f;
  for (int i = 0; i < D_EMB / 64; i++) {
    int d = i * 64 + lane;
    if (isbf) {
      float xv = bf2f(x16[(size_t)t * D_EMB + d]);
      const unsigned short* g = gw16 + d * NE;
#pragma unroll
      for (int e = 0; e < NE; e++) acc[e] += xv * bf2f(g[e]);
    } else {
      float xv = x32[(size_t)t * D_EMB + d];
      const float* g = gw32 + d * NE;
#pragma unroll
      for (int e = 0; e < NE; e++) acc[e] += xv * g[e];
    }
  }
  __shared__ __align__(16) float sacc[64][NE + 1];
#pragma unroll
  for (int e = 0; e < NE; e++) sacc[lane][e] = acc[e];
  __syncthreads();
  __shared__ float sc[NE];
  if (lane < NE) {
    float s = 0.f;
    for (int i = 0; i < 64; i++) s += sacc[i][lane];
    sc[lane] = s + (isbf ? bf2f(gb16[lane]) : gb32[lane]);
  }
  __syncthreads();
  if (lane == 0) {
    float sv[NE];
    sv[0] = -1e9f;                        // masked shared-expert logit
    for (int e = 1; e < NE; e++) sv[e] = sc[e];
    float m = sv[1];
    for (int e = 2; e < NE; e++) m = fmaxf(m, sv[e]);
    float pr[NE]; float den = 0.f;
    for (int e = 0; e < NE; e++) { pr[e] = expf(sv[e] - m); den += pr[e]; }
    float inv = 1.f / den;
    for (int e = 0; e < NE; e++) pr[e] *= inv;   // pr[0] == 0 exactly
    psel[t * 4] = 0; pw[t * 4] = 1.0f;           // shared expert, weight 1
    int pos = atomicAdd(&cnt[0], 1);
    plist[pos] = t * 4;
    bool used[NE];
    for (int e = 0; e < NE; e++) used[e] = false;
    for (int k = 0; k < 3; k++) {                // strict >, low idx wins ties
      int best = 1; float bv = -1.f;
      for (int e = 1; e < NE; e++)
        if (!used[e] && pr[e] > bv) { bv = pr[e]; best = e; }
      used[best] = true;
      int p = t * 4 + 1 + k;
      psel[p] = best; pw[p] = bv;
      pos = atomicAdd(&cnt[best], 1);
      plist[best * T_TOK + pos] = p;
    }
  }
}

// ---------------- K2/K4: grouped gathered-A GEMM, MFMA 16x16x32 bf16 --------
template<int KDIM, int NDIM, bool GELU, bool HASBIAS, bool AROWDIV4, bool OUTF32>
__global__ __launch_bounds__(256) void moe_gemm(
    const unsigned short* __restrict__ AO, const unsigned short* __restrict__ AC,
    const unsigned short* __restrict__ BO, const unsigned short* __restrict__ BC,
    const unsigned short* __restrict__ biasO, const unsigned short* __restrict__ biasC,
    const int* __restrict__ flag,
    const int* __restrict__ cnt, const int* __restrict__ plist,
    unsigned short* __restrict__ outB, float* __restrict__ outF)
{
  int bx  = blockIdx.x;
  int e   = bx / (32 * NSPLIT);
  int rem = bx % (32 * NSPLIT);
  int mt  = rem / NSPLIT;
  int ns  = rem % NSPLIT;
  int count = cnt[e];
  if (mt * MT >= count) return;
  int isbf = *flag;
  const unsigned short* Abase   = isbf ? AO : AC;
  const unsigned short* Ball    = isbf ? BO : BC;
  const unsigned short* biasAll = isbf ? biasO : biasC;

  __shared__ __align__(16) int sp[MT];
  __shared__ __align__(16) unsigned short bT[NCH][KCH + 8];   // [n][k]

  if (threadIdx.x < MT) {
    int rg  = mt * MT + threadIdx.x;
    int idx = rg < count ? rg : count - 1;      // duplicate last row (pad)
    sp[threadIdx.x] = plist[e * T_TOK + idx];
  }
  __syncthreads();

  const unsigned short* B = Ball + (size_t)e * KDIM * NDIM;
  int wave = threadIdx.x >> 6;
  int lane = threadIdx.x & 63;
  int m16  = lane & 15;
  int quad = lane >> 4;
  int p_a  = sp[wave * 16 + m16];
  const unsigned short* Arow =
      Abase + (size_t)(AROWDIV4 ? (p_a >> 2) : p_a) * KDIM;

  const int NPB = NDIM / NSPLIT;
  for (int n0 = ns * NPB; n0 < (ns + 1) * NPB; n0 += NCH) {
    floatx4 acc[4];
#pragma unroll
    for (int i = 0; i < 4; i++) acc[i] = (floatx4){0.f, 0.f, 0.f, 0.f};

    for (int k0 = 0; k0 < KDIM; k0 += KCH) {
      __syncthreads();                          // bT reuse fence
#pragma unroll
      for (int it = 0; it < 4; it++) {
        int li  = it * 256 + threadIdx.x;
        int kk  = li >> 3;
        int nn8 = (li & 7) << 3;
        ushort8 v = *(const ushort8*)(B + (size_t)(k0 + kk) * NDIM + n0 + nn8);
#pragma unroll
        for (int j = 0; j < 8; j++) bT[nn8 + j][kk] = v[j];
      }
      __syncthreads();
#pragma unroll
      for (int ks = 0; ks < KCH / 32; ks++) {
        short8 af = *(const short8*)(Arow + k0 + ks * 32 + quad * 8);
#pragma unroll
        for (int nt = 0; nt < 4; nt++) {
          short8 bfg = *(const short8*)(&bT[nt * 16 + m16][ks * 32 + quad * 8]);
          acc[nt] = __builtin_amdgcn_mfma_f32_16x16x32_bf16(af, bfg, acc[nt], 0, 0, 0);
        }
      }
    }
    // epilogue: C/D layout col = lane&15, row = quad*4 + reg
#pragma unroll
    for (int nt = 0; nt < 4; nt++) {
#pragma unroll
      for (int r = 0; r < 4; r++) {
        int row_local = wave * 16 + quad * 4 + r;
        int rg = mt * MT + row_local;
        if (rg < count) {
          int col = n0 + nt * 16 + m16;
          float v = acc[nt][r];
          if (HASBIAS) v += bf2f(biasAll[e * NDIM + col]);
          if (GELU)    v = 0.5f * v * (1.f + erff(v * 0.70710678118654752f));
          int p = sp[row_local];
          if (OUTF32) outF[(size_t)p * NDIM + col] = v;
          else        outB[(size_t)p * NDIM + col] = f2bf(v);
        }
      }
    }
  }
}

// ---------------- K3: LayerNorm per pair, combine weight folded in ----------
__global__ __launch_bounds__(256) void ln_kernel(
    unsigned short* __restrict__ Hbuf,
    const unsigned short* __restrict__ lnwO, const unsigned short* __restrict__ lnwC,
    const unsigned short* __restrict__ lnbO, const unsigned short* __restrict__ lnbC,
    const int* __restrict__ psel, const float* __restrict__ pw,
    const int* __restrict__ flag)
{
  int p = blockIdx.x;
  int e = psel[p];
  int isbf = *flag;
  const unsigned short* lnw = isbf ? lnwO : lnwC;
  const unsigned short* lnb = isbf ? lnbO : lnbC;
  unsigned short* hr = Hbuf + (size_t)p * H_FFN;
  int tid = threadIdx.x;
  float vals[6];
  float s = 0.f, sq = 0.f;
#pragma unroll
  for (int i = 0; i < 6; i++) {
    float v = bf2f(hr[i * 256 + tid]);
    vals[i] = v; s += v; sq += v * v;
  }
#pragma unroll
  for (int off = 32; off > 0; off >>= 1) {
    s  += __shfl_down(s, off);
    sq += __shfl_down(sq, off);
  }
  __shared__ float red[8];
  int wave = tid >> 6, lane = tid & 63;
  if (lane == 0) { red[wave * 2] = s; red[wave * 2 + 1] = sq; }
  __syncthreads();
  __shared__ float mv[2];
  if (tid == 0) {
    float S = 0.f, Q = 0.f;
    for (int w = 0; w < 4; w++) { S += red[w * 2]; Q += red[w * 2 + 1]; }
    float mu  = S * (1.f / H_FFN);
    float var = Q * (1.f / H_FFN) - mu * mu;   // biased var = jnp.var
    mv[0] = mu; mv[1] = rsqrtf(var + 1e-5f);
  }
  __syncthreads();
  float mu = mv[0], rstd = mv[1];
  float w = pw[p];
#pragma unroll
  for (int i = 0; i < 6; i++) {
    int h = i * 256 + tid;
    float v = (vals[i] - mu) * rstd * bf2f(lnw[e * H_FFN + h]) + bf2f(lnb[e * H_FFN + h]);
    hr[h] = f2bf(v * w);                       // fold combine weight
  }
}

// ---------------- K5: sum 4 pair outputs + weighted fc2 bias ----------------
__global__ __launch_bounds__(256) void combine_kernel(
    const float* __restrict__ Y,
    const unsigned short* __restrict__ b2O, const unsigned short* __restrict__ b2C,
    const int* __restrict__ psel, const float* __restrict__ pw,
    unsigned short* __restrict__ out16, float* __restrict__ out32,
    const int* __restrict__ flag)
{
  int t = blockIdx.x;
  int tid = threadIdx.x;
  int isbf = *flag;
  const unsigned short* b2 = isbf ? b2O : b2C;
  int e1 = psel[t * 4 + 1], e2 = psel[t * 4 + 2], e3 = psel[t * 4 + 3];
  float w1 = pw[t * 4 + 1], w2 = pw[t * 4 + 2], w3 = pw[t * 4 + 3];
#pragma unroll
  for (int i = 0; i < 3; i++) {
    int d = i * 256 + tid;
    float a = Y[(size_t)(t * 4 + 0) * D_EMB + d]
            + Y[(size_t)(t * 4 + 1) * D_EMB + d]
            + Y[(size_t)(t * 4 + 2) * D_EMB + d]
            + Y[(size_t)(t * 4 + 3) * D_EMB + d];
    a += bf2f(b2[d]);                          // expert 0, weight 1
    a += w1 * bf2f(b2[e1 * D_EMB + d])
       + w2 * bf2f(b2[e2 * D_EMB + d])
       + w3 * bf2f(b2[e3 * D_EMB + d]);
    if (isbf) out16[(size_t)t * D_EMB + d] = f2bf(a);
    else      out32[(size_t)t * D_EMB + d] = a;
  }
}

extern "C" void kernel_launch(void* const* d_in, const int* in_sizes, int n_in,
                              void* d_out, int out_size, void* d_ws, size_t ws_size,
                              hipStream_t stream)
{
  (void)in_sizes; (void)n_in; (void)out_size; (void)ws_size;
  char* ws = (char*)d_ws;
  int*   cnt   = (int*)ws;                                   // 16 ints
  int*   plist = (int*)(ws + 256);                           // 16*2048 ints
  int*   psel  = (int*)(ws + 131328);                        // 8192 ints
  float* pw    = (float*)(ws + 164096);                      // 8192 f32
  int*   flag  = (int*)(ws + 196864);
  unsigned short* Hbuf = (unsigned short*)(ws + 262144);     // 8192*1536 bf16
  float* Ybuf  = (float*)(ws + 25427968);                    // 8192*768 f32
  char*  convB = ws + 50593792;                              // bf16 canon area

  static const int nseg[9] = {1572864, 12288, 16, 18874368, 24576,
                              24576, 24576, 18874368, 12288};
  unsigned short* conv[9];
  {
    size_t off = 0;
    for (int i = 0; i < 9; i++) { conv[i] = (unsigned short*)(convB + off); off += (size_t)nseg[i] * 2; }
  }
  int total = 0;
  for (int i = 0; i < 9; i++) total += nseg[i];

  hipMemsetAsync(cnt, 0, 64, stream);
  sniff_kernel<<<1, 64, 0, stream>>>((const unsigned int*)d_in[0], flag);

  ConvArgs ca;
  for (int i = 0; i < 9; i++) { ca.src[i] = (const float*)d_in[i]; ca.dst[i] = conv[i]; ca.n[i] = nseg[i]; }
  conv_kernel<<<8192, 256, 0, stream>>>(ca, flag, total);

  gate_kernel<<<T_TOK, 64, 0, stream>>>(
      (const unsigned short*)d_in[0], (const float*)d_in[0],
      (const unsigned short*)d_in[1], (const float*)d_in[1],
      (const unsigned short*)d_in[2], (const float*)d_in[2],
      flag, cnt, plist, psel, pw);

  moe_gemm<D_EMB, H_FFN, true, true, true, false>
      <<<NE * 32 * NSPLIT, 256, 0, stream>>>(
      (const unsigned short*)d_in[0], conv[0],
      (const unsigned short*)d_in[3], conv[3],
      (const unsigned short*)d_in[4], conv[4],
      flag, cnt, plist, Hbuf, nullptr);

  ln_kernel<<<NPAIR, 256, 0, stream>>>(
      Hbuf,
      (const unsigned short*)d_in[5], conv[5],
      (const unsigned short*)d_in[6], conv[6],
      psel, pw, flag);

  moe_gemm<H_FFN, D_EMB, false, false, false, true>
      <<<NE * 32 * NSPLIT, 256, 0, stream>>>(
      Hbuf, Hbuf,
      (const unsigned short*)d_in[7], conv[7],
      nullptr, nullptr,
      flag, cnt, plist, nullptr, Ybuf);

  combine_kernel<<<T_TOK, 256, 0, stream>>>(
      Ybuf,
      (const unsigned short*)d_in[8], conv[8],
      psel, pw,
      (unsigned short*)d_out, (float*)d_out, flag);
}

// Round 3
// 448.735 us; speedup vs baseline: 1.7059x; 1.7059x over previous
//
#include <hip/hip_runtime.h>
#include <cmath>

#define T_TOK 2048
#define D_EMB 768
#define H_FFN 1536
#define NE    16
#define NPAIR (T_TOK * 4)

typedef __attribute__((ext_vector_type(8))) short          short8;
typedef __attribute__((ext_vector_type(8))) unsigned short ushort8;
typedef __attribute__((ext_vector_type(4))) unsigned short ushort4v;
typedef __attribute__((ext_vector_type(4))) float          floatx4;

__device__ __forceinline__ float bf2f(unsigned short u) {
  union { unsigned int i; float f; } v; v.i = ((unsigned int)u) << 16; return v.f;
}
__device__ __forceinline__ unsigned short f2bf(float f) {
  union { float f; unsigned int i; } v; v.f = f;
  unsigned int r = v.i + 0x7fffu + ((v.i >> 16) & 1u);   // RNE
  return (unsigned short)(r >> 16);
}

// ---------------- K0: dtype sniff (1 = inputs are bf16) ---------------------
__global__ __launch_bounds__(64) void sniff_kernel(
    const unsigned int* __restrict__ x, int* __restrict__ flag)
{
  int lane = threadIdx.x;
  int c = 0;
  for (int i = 0; i < 8; i++) {
    unsigned int w = x[i * 64 + lane];
    unsigned int e = (w >> 7) & 0xFFu;
    c += (e >= 100u && e <= 140u) ? 1 : 0;
  }
  for (int off = 32; off > 0; off >>= 1) c += __shfl_down(c, off);
  if (lane == 0) *flag = (c > 300) ? 1 : 0;
}

// ---------------- K0b: f32 -> bf16 for x + small vectors (f32 mode only) ----
__global__ __launch_bounds__(256) void conv_kernel(
    const float* __restrict__ x, const float* __restrict__ fc1b,
    const float* __restrict__ lnw, const float* __restrict__ lnb,
    const float* __restrict__ fc2b,
    unsigned short* __restrict__ dx, unsigned short* __restrict__ dfc1b,
    unsigned short* __restrict__ dlnw, unsigned short* __restrict__ dlnb,
    unsigned short* __restrict__ dfc2b, const int* __restrict__ flag)
{
  if (*flag) return;
  int g = blockIdx.x * 256 + threadIdx.x;          // grid 2048*256 = 524288
#pragma unroll
  for (int i = 0; i < 3; i++) dx[g + i * 524288] = f2bf(x[g + i * 524288]);
  if (g < 24576) { dfc1b[g] = f2bf(fc1b[g]); dlnw[g] = f2bf(lnw[g]); dlnb[g] = f2bf(lnb[g]); }
  if (g < 12288) dfc2b[g] = f2bf(fc2b[g]);
}

// ---------------- K0c: weight transpose [e][R][C] -> [e][C][R] bf16 ---------
// XOR-swizzled LDS tile: conflict-free writes, ~free reads.
template<int R, int C>
__global__ __launch_bounds__(256) void transpose_kernel(
    const unsigned short* __restrict__ srcB, const float* __restrict__ srcF,
    const int* __restrict__ flag, unsigned short* __restrict__ dst)
{
  __shared__ __align__(16) unsigned short tile[64][72];
  constexpr int RT = R / 64, CT = C / 64;
  int bx  = blockIdx.x;
  int e   = bx / (RT * CT);
  int rem = bx % (RT * CT);
  int rt  = rem / CT, ct = rem % CT;
  int tid = threadIdx.x;
  int r   = tid >> 2;
  int c   = (tid & 3) * 16;
  int xr  = (r & 7) * 8;                       // XOR swizzle per row
  size_t sbase = ((size_t)e * R + rt * 64 + r) * C + ct * 64 + c;
  if (*flag) {
    ushort8 v0 = *(const ushort8*)(srcB + sbase);
    ushort8 v1 = *(const ushort8*)(srcB + sbase + 8);
    *(ushort8*)&tile[r][(c) ^ xr]     = v0;
    *(ushort8*)&tile[r][(c + 8) ^ xr] = v1;
  } else {
    unsigned short tmp[16];
#pragma unroll
    for (int q = 0; q < 4; q++) {
      floatx4 f = *(const floatx4*)(srcF + sbase + q * 4);
#pragma unroll
      for (int j = 0; j < 4; j++) tmp[q * 4 + j] = f2bf(f[j]);
    }
    *(ushort8*)&tile[r][(c) ^ xr]     = *(ushort8*)&tmp[0];
    *(ushort8*)&tile[r][(c + 8) ^ xr] = *(ushort8*)&tmp[8];
  }
  __syncthreads();
  int n  = tid >> 2;
  int k  = (tid & 3) * 16;
  unsigned short outv[16];
#pragma unroll
  for (int j = 0; j < 16; j++) {
    int kr = k + j;
    outv[j] = tile[kr][n ^ ((kr & 7) * 8)];
  }
  size_t dbase = ((size_t)e * C + ct * 64 + n) * R + rt * 64 + k;
  *(ushort8*)(dst + dbase)     = *(ushort8*)&outv[0];
  *(ushort8*)(dst + dbase + 8) = *(ushort8*)&outv[8];
}

// ---------------- K1: gating ------------------------------------------------
__global__ __launch_bounds__(64) void gate_kernel(
    const unsigned short* __restrict__ x16, const float* __restrict__ x32,
    const unsigned short* __restrict__ gw16, const float* __restrict__ gw32,
    const unsigned short* __restrict__ gb16, const float* __restrict__ gb32,
    const int* __restrict__ flag,
    int* __restrict__ cnt, int* __restrict__ plist,
    int* __restrict__ psel, float* __restrict__ pw)
{
  int t = blockIdx.x;
  int lane = threadIdx.x;
  int isbf = *flag;
  float acc[NE];
#pragma unroll
  for (int e = 0; e < NE; e++) acc[e] = 0.f;
  for (int i = 0; i < D_EMB / 64; i++) {
    int d = i * 64 + lane;
    if (isbf) {
      float xv = bf2f(x16[(size_t)t * D_EMB + d]);
      ushort8 g0 = *(const ushort8*)(gw16 + d * NE);
      ushort8 g1 = *(const ushort8*)(gw16 + d * NE + 8);
#pragma unroll
      for (int e = 0; e < 8; e++) acc[e]     += xv * bf2f(g0[e]);
#pragma unroll
      for (int e = 0; e < 8; e++) acc[8 + e] += xv * bf2f(g1[e]);
    } else {
      float xv = x32[(size_t)t * D_EMB + d];
#pragma unroll
      for (int q = 0; q < 4; q++) {
        floatx4 g = *(const floatx4*)(gw32 + d * NE + q * 4);
#pragma unroll
        for (int j = 0; j < 4; j++) acc[q * 4 + j] += xv * g[j];
      }
    }
  }
  __shared__ __align__(16) float sacc[64][NE + 1];
#pragma unroll
  for (int e = 0; e < NE; e++) sacc[lane][e] = acc[e];
  __syncthreads();
  __shared__ float sc[NE];
  if (lane < NE) {
    float s = 0.f;
    for (int i = 0; i < 64; i++) s += sacc[i][lane];
    sc[lane] = s + (isbf ? bf2f(gb16[lane]) : gb32[lane]);
  }
  __syncthreads();
  if (lane == 0) {
    float sv[NE];
    sv[0] = -1e9f;                         // masked shared-expert logit
    for (int e = 1; e < NE; e++) sv[e] = sc[e];
    float m = sv[1];
    for (int e = 2; e < NE; e++) m = fmaxf(m, sv[e]);
    float pr[NE]; float den = 0.f;
    for (int e = 0; e < NE; e++) { pr[e] = expf(sv[e] - m); den += pr[e]; }
    float inv = 1.f / den;
    for (int e = 0; e < NE; e++) pr[e] *= inv;   // pr[0] == 0 exactly
    psel[t * 4] = 0; pw[t * 4] = 1.0f;
    int pos = atomicAdd(&cnt[0], 1);
    plist[pos] = t * 4;
    bool used[NE];
    for (int e = 0; e < NE; e++) used[e] = false;
    for (int k = 0; k < 3; k++) {          // strict >, low idx wins ties
      int best = 1; float bv = -1.f;
      for (int e = 1; e < NE; e++)
        if (!used[e] && pr[e] > bv) { bv = pr[e]; best = e; }
      used[best] = true;
      int p = t * 4 + 1 + k;
      psel[p] = best; pw[p] = bv;
      pos = atomicAdd(&cnt[best], 1);
      plist[best * T_TOK + pos] = p;
    }
  }
}

// ---------------- K2/K4: grouped GEMM, B^T layout, conflict-free LDS --------
// Block: 64 rows x 128 cols, KCH=64. 4 waves as 2x2 -> wave tile 32x64.
template<int KDIM, int NDIM, bool GELU, bool HASBIAS, bool AROWDIV4, bool OUTF32>
__global__ __launch_bounds__(256) void moe_gemm(
    const unsigned short* __restrict__ AO, const unsigned short* __restrict__ AC,
    const unsigned short* __restrict__ BT,       // [e][NDIM][KDIM]
    const unsigned short* __restrict__ biasO, const unsigned short* __restrict__ biasC,
    const int* __restrict__ flag,
    const int* __restrict__ cnt, const int* __restrict__ plist,
    unsigned short* __restrict__ outB, float* __restrict__ outF)
{
  const int NSP = NDIM / 128;
  int bx  = blockIdx.x;
  int e   = bx / (32 * NSP);
  int rem = bx % (32 * NSP);
  int mt  = rem / NSP;
  int ns  = rem % NSP;
  int count = cnt[e];
  if (mt * 64 >= count) return;
  const unsigned short* Abase   = (*flag) ? AO : AC;
  const unsigned short* biasAll = (*flag) ? biasO : biasC;

  __shared__ __align__(16) unsigned short sA[64][72];
  __shared__ __align__(16) unsigned short sB[128][72];
  __shared__ int sp[64];

  int tid = threadIdx.x;
  if (tid < 64) {
    int rg  = mt * 64 + tid;
    int idx = rg < count ? rg : count - 1;    // duplicate last row (pad)
    sp[tid] = plist[e * T_TOK + idx];
  }
  __syncthreads();

  int arow = tid >> 3;                        // 0..31
  int ac8  = (tid & 7) * 8;
  int pr0 = sp[arow], pr1 = sp[arow + 32];
  const unsigned short* Aptr0 = Abase + (size_t)(AROWDIV4 ? (pr0 >> 2) : pr0) * KDIM + ac8;
  const unsigned short* Aptr1 = Abase + (size_t)(AROWDIV4 ? (pr1 >> 2) : pr1) * KDIM + ac8;
  int n0 = ns * 128;
  const unsigned short* Bptr =
      BT + ((size_t)e * NDIM + n0 + arow) * KDIM + ac8;

  int lane = tid & 63;
  int wave = tid >> 6;
  int wm   = (wave >> 1) * 32;
  int wn   = (wave & 1) * 64;
  int m16  = lane & 15;
  int quad = lane >> 4;

  floatx4 acc[2][4];
#pragma unroll
  for (int i = 0; i < 2; i++)
#pragma unroll
    for (int j = 0; j < 4; j++) acc[i][j] = (floatx4){0.f, 0.f, 0.f, 0.f};

  ushort8 pa0 = *(const ushort8*)(Aptr0);
  ushort8 pa1 = *(const ushort8*)(Aptr1);
  ushort8 pb0 = *(const ushort8*)(Bptr);
  ushort8 pb1 = *(const ushort8*)(Bptr + (size_t)32 * KDIM);
  ushort8 pb2 = *(const ushort8*)(Bptr + (size_t)64 * KDIM);
  ushort8 pb3 = *(const ushort8*)(Bptr + (size_t)96 * KDIM);

  for (int k0 = 0; k0 < KDIM; k0 += 64) {
    __syncthreads();                          // LDS reads of prev iter done
    *(ushort8*)&sA[arow][ac8]       = pa0;
    *(ushort8*)&sA[arow + 32][ac8]  = pa1;
    *(ushort8*)&sB[arow][ac8]       = pb0;
    *(ushort8*)&sB[arow + 32][ac8]  = pb1;
    *(ushort8*)&sB[arow + 64][ac8]  = pb2;
    *(ushort8*)&sB[arow + 96][ac8]  = pb3;
    __syncthreads();
    if (k0 + 64 < KDIM) {                     // prefetch next chunk
      pa0 = *(const ushort8*)(Aptr0 + k0 + 64);
      pa1 = *(const ushort8*)(Aptr1 + k0 + 64);
      pb0 = *(const ushort8*)(Bptr + k0 + 64);
      pb1 = *(const ushort8*)(Bptr + k0 + 64 + (size_t)32 * KDIM);
      pb2 = *(const ushort8*)(Bptr + k0 + 64 + (size_t)64 * KDIM);
      pb3 = *(const ushort8*)(Bptr + k0 + 64 + (size_t)96 * KDIM);
    }
#pragma unroll
    for (int ks = 0; ks < 2; ks++) {
      short8 af0 = *(const short8*)&sA[wm + m16][ks * 32 + quad * 8];
      short8 af1 = *(const short8*)&sA[wm + 16 + m16][ks * 32 + quad * 8];
#pragma unroll
      for (int nt = 0; nt < 4; nt++) {
        short8 bfg = *(const short8*)&sB[wn + nt * 16 + m16][ks * 32 + quad * 8];
        acc[0][nt] = __builtin_amdgcn_mfma_f32_16x16x32_bf16(af0, bfg, acc[0][nt], 0, 0, 0);
        acc[1][nt] = __builtin_amdgcn_mfma_f32_16x16x32_bf16(af1, bfg, acc[1][nt], 0, 0, 0);
      }
    }
  }
  // epilogue: C/D col = lane&15 (-> n), row = quad*4 + reg (-> m)
#pragma unroll
  for (int sub = 0; sub < 2; sub++) {
#pragma unroll
    for (int nt = 0; nt < 4; nt++) {
#pragma unroll
      for (int r = 0; r < 4; r++) {
        int row_local = wm + sub * 16 + quad * 4 + r;
        int rg = mt * 64 + row_local;
        if (rg < count) {
          int col = n0 + wn + nt * 16 + m16;
          float v = acc[sub][nt][r];
          if (HASBIAS) v += bf2f(biasAll[e * NDIM + col]);
          if (GELU)    v = 0.5f * v * (1.f + erff(v * 0.70710678118654752f));
          int p = sp[row_local];
          if (OUTF32) outF[(size_t)p * NDIM + col] = v;
          else        outB[(size_t)p * NDIM + col] = f2bf(v);
        }
      }
    }
  }
}

// ---------------- K3: LayerNorm per pair, combine weight folded in ----------
__global__ __launch_bounds__(256) void ln_kernel(
    unsigned short* __restrict__ Hbuf,
    const unsigned short* __restrict__ lnwO, const unsigned short* __restrict__ lnwC,
    const unsigned short* __restrict__ lnbO, const unsigned short* __restrict__ lnbC,
    const int* __restrict__ psel, const float* __restrict__ pw,
    const int* __restrict__ flag)
{
  int p = blockIdx.x;
  int tid = threadIdx.x;
  int e = psel[p];
  int isbf = *flag;
  const unsigned short* lnw = isbf ? lnwO : lnwC;
  const unsigned short* lnb = isbf ? lnbO : lnbC;
  unsigned short* hr = Hbuf + (size_t)p * H_FFN;
  bool act = tid < 192;                       // 192*8 = 1536
  float v[8];
  float s = 0.f, sq = 0.f;
  if (act) {
    ushort8 hv = *(const ushort8*)(hr + tid * 8);
#pragma unroll
    for (int j = 0; j < 8; j++) { v[j] = bf2f(hv[j]); s += v[j]; sq += v[j] * v[j]; }
  }
#pragma unroll
  for (int off = 32; off > 0; off >>= 1) {
    s  += __shfl_down(s, off);
    sq += __shfl_down(sq, off);
  }
  __shared__ float red[8];
  int wave = tid >> 6, lane = tid & 63;
  if (lane == 0) { red[wave * 2] = s; red[wave * 2 + 1] = sq; }
  __syncthreads();
  __shared__ float mv[2];
  if (tid == 0) {
    float S = 0.f, Q = 0.f;
    for (int w = 0; w < 4; w++) { S += red[w * 2]; Q += red[w * 2 + 1]; }
    float mu  = S * (1.f / H_FFN);
    float var = Q * (1.f / H_FFN) - mu * mu;  // biased var = jnp.var
    mv[0] = mu; mv[1] = rsqrtf(var + 1e-5f);
  }
  __syncthreads();
  if (act) {
    float mu = mv[0], rstd = mv[1];
    float w = pw[p];
    ushort8 lw = *(const ushort8*)(lnw + e * H_FFN + tid * 8);
    ushort8 lb = *(const ushort8*)(lnb + e * H_FFN + tid * 8);
    ushort8 o;
#pragma unroll
    for (int j = 0; j < 8; j++)
      o[j] = f2bf(((v[j] - mu) * rstd * bf2f(lw[j]) + bf2f(lb[j])) * w);
    *(ushort8*)(hr + tid * 8) = o;
  }
}

// ---------------- K5: sum 4 pair outputs + weighted fc2 bias ----------------
__global__ __launch_bounds__(256) void combine_kernel(
    const float* __restrict__ Y,
    const unsigned short* __restrict__ b2O, const unsigned short* __restrict__ b2C,
    const int* __restrict__ psel, const float* __restrict__ pw,
    unsigned short* __restrict__ out16, float* __restrict__ out32,
    const int* __restrict__ flag)
{
  int t = blockIdx.x;
  int tid = threadIdx.x;
  if (tid >= 192) return;                     // 192*4 = 768
  int isbf = *flag;
  const unsigned short* b2 = isbf ? b2O : b2C;
  int e1 = psel[t * 4 + 1], e2 = psel[t * 4 + 2], e3 = psel[t * 4 + 3];
  float w1 = pw[t * 4 + 1], w2 = pw[t * 4 + 2], w3 = pw[t * 4 + 3];
  int d = tid * 4;
  const float* Yb = Y + (size_t)t * 4 * D_EMB + d;
  floatx4 y0 = *(const floatx4*)(Yb);
  floatx4 y1 = *(const floatx4*)(Yb + D_EMB);
  floatx4 y2 = *(const floatx4*)(Yb + 2 * D_EMB);
  floatx4 y3 = *(const floatx4*)(Yb + 3 * D_EMB);
  ushort4v b0 = *(const ushort4v*)(b2 + d);
  ushort4v bb1 = *(const ushort4v*)(b2 + e1 * D_EMB + d);
  ushort4v bb2 = *(const ushort4v*)(b2 + e2 * D_EMB + d);
  ushort4v bb3 = *(const ushort4v*)(b2 + e3 * D_EMB + d);
  if (isbf) {
    ushort4v o;
#pragma unroll
    for (int j = 0; j < 4; j++) {
      float a = y0[j] + y1[j] + y2[j] + y3[j] + bf2f(b0[j])
              + w1 * bf2f(bb1[j]) + w2 * bf2f(bb2[j]) + w3 * bf2f(bb3[j]);
      o[j] = f2bf(a);
    }
    *(ushort4v*)(out16 + (size_t)t * D_EMB + d) = o;
  } else {
    floatx4 o;
#pragma unroll
    for (int j = 0; j < 4; j++)
      o[j] = y0[j] + y1[j] + y2[j] + y3[j] + bf2f(b0[j])
           + w1 * bf2f(bb1[j]) + w2 * bf2f(bb2[j]) + w3 * bf2f(bb3[j]);
    *(floatx4*)(out32 + (size_t)t * D_EMB + d) = o;
  }
}

extern "C" void kernel_launch(void* const* d_in, const int* in_sizes, int n_in,
                              void* d_out, int out_size, void* d_ws, size_t ws_size,
                              hipStream_t stream)
{
  (void)in_sizes; (void)n_in; (void)out_size; (void)ws_size;
  char* ws = (char*)d_ws;
  int*   cnt   = (int*)ws;                                 // 16 ints
  int*   plist = (int*)(ws + 256);                         // 16*2048 ints
  int*   psel  = (int*)(ws + 131328);                      // 8192 ints
  float* pw    = (float*)(ws + 164096);                    // 8192 f32
  int*   flag  = (int*)(ws + 196864);
  unsigned short* fc1bC = (unsigned short*)(ws + 197120);  // 24576 bf16
  unsigned short* lnwC  = (unsigned short*)(ws + 246272);
  unsigned short* lnbC  = (unsigned short*)(ws + 295424);
  unsigned short* fc2bC = (unsigned short*)(ws + 344576);  // 12288 bf16
  unsigned short* xC    = (unsigned short*)(ws + 524288);  // 1572864 bf16
  unsigned short* Hbuf  = (unsigned short*)(ws + 3670016); // 8192*1536 bf16
  float*          Ybuf  = (float*)(ws + 28835840);         // 8192*768 f32
  unsigned short* fc1T  = (unsigned short*)(ws + 54001664);// [16][1536][768] bf16
  unsigned short* fc2T  = (unsigned short*)(ws + 91750400);// [16][768][1536] bf16

  hipMemsetAsync(cnt, 0, 64, stream);
  sniff_kernel<<<1, 64, 0, stream>>>((const unsigned int*)d_in[0], flag);

  conv_kernel<<<2048, 256, 0, stream>>>(
      (const float*)d_in[0], (const float*)d_in[4], (const float*)d_in[5],
      (const float*)d_in[6], (const float*)d_in[8],
      xC, fc1bC, lnwC, lnbC, fc2bC, flag);

  transpose_kernel<768, 1536><<<16 * 12 * 24, 256, 0, stream>>>(
      (const unsigned short*)d_in[3], (const float*)d_in[3], flag, fc1T);
  transpose_kernel<1536, 768><<<16 * 24 * 12, 256, 0, stream>>>(
      (const unsigned short*)d_in[7], (const float*)d_in[7], flag, fc2T);

  gate_kernel<<<T_TOK, 64, 0, stream>>>(
      (const unsigned short*)d_in[0], (const float*)d_in[0],
      (const unsigned short*)d_in[1], (const float*)d_in[1],
      (const unsigned short*)d_in[2], (const float*)d_in[2],
      flag, cnt, plist, psel, pw);

  moe_gemm<D_EMB, H_FFN, true, true, true, false>
      <<<NE * 32 * (H_FFN / 128), 256, 0, stream>>>(
      (const unsigned short*)d_in[0], xC, fc1T,
      (const unsigned short*)d_in[4], fc1bC,
      flag, cnt, plist, Hbuf, nullptr);

  ln_kernel<<<NPAIR, 256, 0, stream>>>(
      Hbuf,
      (const unsigned short*)d_in[5], lnwC,
      (const unsigned short*)d_in[6], lnbC,
      psel, pw, flag);

  moe_gemm<H_FFN, D_EMB, false, false, false, true>
      <<<NE * 32 * (D_EMB / 128), 256, 0, stream>>>(
      Hbuf, Hbuf, fc2T,
      nullptr, nullptr,
      flag, cnt, plist, nullptr, Ybuf);

  combine_kernel<<<T_TOK, 256, 0, stream>>>(
      Ybuf,
      (const unsigned short*)d_in[8], fc2bC,
      psel, pw,
      (unsigned short*)d_out, (float*)d_out, flag);
}

// Round 4
// 425.207 us; speedup vs baseline: 1.8003x; 1.0553x over previous
//
#include <hip/hip_runtime.h>
#include <cmath>

#define T_TOK 2048
#define D_EMB 768
#define H_FFN 1536
#define NE    16
#define NPAIR (T_TOK * 4)

typedef __attribute__((ext_vector_type(8))) short          short8;
typedef __attribute__((ext_vector_type(8))) unsigned short ushort8;
typedef __attribute__((ext_vector_type(4))) unsigned short ushort4v;
typedef __attribute__((ext_vector_type(4))) float          floatx4;

__device__ __forceinline__ float bf2f(unsigned short u) {
  union { unsigned int i; float f; } v; v.i = ((unsigned int)u) << 16; return v.f;
}
__device__ __forceinline__ unsigned short f2bf(float f) {
  union { float f; unsigned int i; } v; v.f = f;
  unsigned int r = v.i + 0x7fffu + ((v.i >> 16) & 1u);   // RNE
  return (unsigned short)(r >> 16);
}

// ---------------- K0: dtype sniff (1 = inputs are bf16) ---------------------
__global__ __launch_bounds__(64) void sniff_kernel(
    const unsigned int* __restrict__ x, int* __restrict__ flag)
{
  int lane = threadIdx.x;
  int c = 0;
  for (int i = 0; i < 8; i++) {
    unsigned int w = x[i * 64 + lane];
    unsigned int e = (w >> 7) & 0xFFu;
    c += (e >= 100u && e <= 140u) ? 1 : 0;
  }
  for (int off = 32; off > 0; off >>= 1) c += __shfl_down(c, off);
  if (lane == 0) *flag = (c > 300) ? 1 : 0;
}

// ---------------- K0b: f32 -> bf16 for x + small vectors (f32 mode only) ----
__global__ __launch_bounds__(256) void conv_kernel(
    const float* __restrict__ x, const float* __restrict__ fc1b,
    const float* __restrict__ lnw, const float* __restrict__ lnb,
    const float* __restrict__ fc2b,
    unsigned short* __restrict__ dx, unsigned short* __restrict__ dfc1b,
    unsigned short* __restrict__ dlnw, unsigned short* __restrict__ dlnb,
    unsigned short* __restrict__ dfc2b, const int* __restrict__ flag)
{
  if (*flag) return;
  int g = blockIdx.x * 256 + threadIdx.x;          // grid 2048*256 = 524288
#pragma unroll
  for (int i = 0; i < 3; i++) dx[g + i * 524288] = f2bf(x[g + i * 524288]);
  if (g < 24576) { dfc1b[g] = f2bf(fc1b[g]); dlnw[g] = f2bf(lnw[g]); dlnb[g] = f2bf(lnb[g]); }
  if (g < 12288) dfc2b[g] = f2bf(fc2b[g]);
}

// ---------------- K0c: weight transpose [e][R][C] -> [e][C][R] bf16 ---------
template<int R, int C>
__global__ __launch_bounds__(256) void transpose_kernel(
    const unsigned short* __restrict__ srcB, const float* __restrict__ srcF,
    const int* __restrict__ flag, unsigned short* __restrict__ dst)
{
  __shared__ __align__(16) unsigned short tile[64][72];
  constexpr int RT = R / 64, CT = C / 64;
  int bx  = blockIdx.x;
  int e   = bx / (RT * CT);
  int rem = bx % (RT * CT);
  int rt  = rem / CT, ct = rem % CT;
  int tid = threadIdx.x;
  int r   = tid >> 2;
  int c   = (tid & 3) * 16;
  int xr  = (r & 7) * 8;                       // XOR swizzle per row
  size_t sbase = ((size_t)e * R + rt * 64 + r) * C + ct * 64 + c;
  if (*flag) {
    ushort8 v0 = *(const ushort8*)(srcB + sbase);
    ushort8 v1 = *(const ushort8*)(srcB + sbase + 8);
    *(ushort8*)&tile[r][(c) ^ xr]     = v0;
    *(ushort8*)&tile[r][(c + 8) ^ xr] = v1;
  } else {
    unsigned short tmp[16];
#pragma unroll
    for (int q = 0; q < 4; q++) {
      floatx4 f = *(const floatx4*)(srcF + sbase + q * 4);
#pragma unroll
      for (int j = 0; j < 4; j++) tmp[q * 4 + j] = f2bf(f[j]);
    }
    *(ushort8*)&tile[r][(c) ^ xr]     = *(ushort8*)&tmp[0];
    *(ushort8*)&tile[r][(c + 8) ^ xr] = *(ushort8*)&tmp[8];
  }
  __syncthreads();
  int n  = tid >> 2;
  int k  = (tid & 3) * 16;
  unsigned short outv[16];
#pragma unroll
  for (int j = 0; j < 16; j++) {
    int kr = k + j;
    outv[j] = tile[kr][n ^ ((kr & 7) * 8)];
  }
  size_t dbase = ((size_t)e * C + ct * 64 + n) * R + rt * 64 + k;
  *(ushort8*)(dst + dbase)     = *(ushort8*)&outv[0];
  *(ushort8*)(dst + dbase + 8) = *(ushort8*)&outv[8];
}

// ---------------- K1: gating, fully wave-parallel ---------------------------
// 1 wave/token. Scores via per-lane partials + LDS transpose + shfl.
// Softmax + top-3 via 16-lane butterflies; no scratch arrays, no serial loops.
__global__ __launch_bounds__(64) void gate_kernel(
    const unsigned short* __restrict__ x16, const float* __restrict__ x32,
    const unsigned short* __restrict__ gw16, const float* __restrict__ gw32,
    const unsigned short* __restrict__ gb16, const float* __restrict__ gb32,
    const int* __restrict__ flag,
    int* __restrict__ cnt, int* __restrict__ plist,
    int* __restrict__ psel, float* __restrict__ pw)
{
  int t = blockIdx.x;
  int lane = threadIdx.x;
  int isbf = *flag;
  float acc[NE];
#pragma unroll
  for (int e = 0; e < NE; e++) acc[e] = 0.f;
  for (int i = 0; i < D_EMB / 64; i++) {
    int d = i * 64 + lane;
    if (isbf) {
      float xv = bf2f(x16[(size_t)t * D_EMB + d]);
      ushort8 g0 = *(const ushort8*)(gw16 + d * NE);
      ushort8 g1 = *(const ushort8*)(gw16 + d * NE + 8);
#pragma unroll
      for (int e = 0; e < 8; e++) acc[e]     += xv * bf2f(g0[e]);
#pragma unroll
      for (int e = 0; e < 8; e++) acc[8 + e] += xv * bf2f(g1[e]);
    } else {
      float xv = x32[(size_t)t * D_EMB + d];
#pragma unroll
      for (int q = 0; q < 4; q++) {
        floatx4 g = *(const floatx4*)(gw32 + d * NE + q * 4);
#pragma unroll
        for (int j = 0; j < 4; j++) acc[q * 4 + j] += xv * g[j];
      }
    }
  }
  __shared__ __align__(16) float sacc[64][NE + 1];
#pragma unroll
  for (int e = 0; e < NE; e++) sacc[lane][e] = acc[e];
  __syncthreads();
  // lane handles expert e = lane&15, quarter q = lane>>4
  int e = lane & 15, q = lane >> 4;
  float s = 0.f;
#pragma unroll
  for (int i = 0; i < 16; i++) s += sacc[q * 16 + i][e];
  s += __shfl_xor(s, 16);
  s += __shfl_xor(s, 32);                     // all lanes: full score for e
  float sv = s + (isbf ? bf2f(gb16[e]) : gb32[e]);
  if (e == 0) sv = -1e9f;                     // masked shared-expert logit
  // softmax over the 16-lane expert group
  float m = sv;
#pragma unroll
  for (int off = 8; off > 0; off >>= 1) m = fmaxf(m, __shfl_xor(m, off));
  float pe = expf(sv - m);                    // e==0 -> underflow to 0
  float den = pe;
#pragma unroll
  for (int off = 8; off > 0; off >>= 1) den += __shfl_xor(den, off);
  float pr = pe / den;                        // pr==0 exactly for e==0
  // top-3: butterfly argmax, strict >, lowest index wins ties (= lax.top_k)
  float val = (e == 0) ? -1.f : pr;
  int sel0, sel1, sel2; float sw0, sw1, sw2;
#pragma unroll
  for (int k = 0; k < 3; k++) {
    float bv = val; int bi = e;
#pragma unroll
    for (int off = 8; off > 0; off >>= 1) {
      float ov = __shfl_xor(bv, off);
      int   oi = __shfl_xor(bi, off);
      if (ov > bv || (ov == bv && oi < bi)) { bv = ov; bi = oi; }
    }
    if (k == 0) { sel0 = bi; sw0 = bv; }
    else if (k == 1) { sel1 = bi; sw1 = bv; }
    else { sel2 = bi; sw2 = bv; }
    if (e == bi) val = -1.f;                  // remove winner
  }
  if (lane == 0) {
    psel[t * 4] = 0; pw[t * 4] = 1.0f;        // shared expert slot
    plist[t] = t * 4;                         // deterministic, token-sorted
    if (t == 0) cnt[0] = T_TOK;
    int p = t * 4 + 1;
    psel[p] = sel0; pw[p] = sw0;
    int pos = atomicAdd(&cnt[sel0], 1);
    plist[sel0 * T_TOK + pos] = p;
    p = t * 4 + 2;
    psel[p] = sel1; pw[p] = sw1;
    pos = atomicAdd(&cnt[sel1], 1);
    plist[sel1 * T_TOK + pos] = p;
    p = t * 4 + 3;
    psel[p] = sel2; pw[p] = sw2;
    pos = atomicAdd(&cnt[sel2], 1);
    plist[sel2 * T_TOK + pos] = p;
  }
}

// ---------------- K2/K4: grouped GEMM, B^T layout, conflict-free LDS --------
// Block: 64 rows x 128 cols, KCH=64. 4 waves as 2x2 -> wave tile 32x64.
template<int KDIM, int NDIM, bool GELU, bool HASBIAS, bool AROWDIV4, bool OUTF32>
__global__ __launch_bounds__(256) void moe_gemm(
    const unsigned short* __restrict__ AO, const unsigned short* __restrict__ AC,
    const unsigned short* __restrict__ BT,       // [e][NDIM][KDIM]
    const unsigned short* __restrict__ biasO, const unsigned short* __restrict__ biasC,
    const int* __restrict__ flag,
    const int* __restrict__ cnt, const int* __restrict__ plist,
    unsigned short* __restrict__ outB, float* __restrict__ outF)
{
  const int NSP = NDIM / 128;
  int bx  = blockIdx.x;
  int e   = bx / (32 * NSP);
  int rem = bx % (32 * NSP);
  int mt  = rem / NSP;
  int ns  = rem % NSP;
  int count = cnt[e];
  if (mt * 64 >= count) return;
  const unsigned short* Abase   = (*flag) ? AO : AC;
  const unsigned short* biasAll = (*flag) ? biasO : biasC;

  __shared__ __align__(16) unsigned short sA[64][72];
  __shared__ __align__(16) unsigned short sB[128][72];
  __shared__ int sp[64];

  int tid = threadIdx.x;
  if (tid < 64) {
    int rg  = mt * 64 + tid;
    int idx = rg < count ? rg : count - 1;    // duplicate last row (pad)
    sp[tid] = plist[e * T_TOK + idx];
  }
  __syncthreads();

  int arow = tid >> 3;                        // 0..31
  int ac8  = (tid & 7) * 8;
  int pr0 = sp[arow], pr1 = sp[arow + 32];
  const unsigned short* Aptr0 = Abase + (size_t)(AROWDIV4 ? (pr0 >> 2) : pr0) * KDIM + ac8;
  const unsigned short* Aptr1 = Abase + (size_t)(AROWDIV4 ? (pr1 >> 2) : pr1) * KDIM + ac8;
  int n0 = ns * 128;
  const unsigned short* Bptr =
      BT + ((size_t)e * NDIM + n0 + arow) * KDIM + ac8;

  int lane = tid & 63;
  int wave = tid >> 6;
  int wm   = (wave >> 1) * 32;
  int wn   = (wave & 1) * 64;
  int m16  = lane & 15;
  int quad = lane >> 4;

  floatx4 acc[2][4];
#pragma unroll
  for (int i = 0; i < 2; i++)
#pragma unroll
    for (int j = 0; j < 4; j++) acc[i][j] = (floatx4){0.f, 0.f, 0.f, 0.f};

  ushort8 pa0 = *(const ushort8*)(Aptr0);
  ushort8 pa1 = *(const ushort8*)(Aptr1);
  ushort8 pb0 = *(const ushort8*)(Bptr);
  ushort8 pb1 = *(const ushort8*)(Bptr + (size_t)32 * KDIM);
  ushort8 pb2 = *(const ushort8*)(Bptr + (size_t)64 * KDIM);
  ushort8 pb3 = *(const ushort8*)(Bptr + (size_t)96 * KDIM);

  for (int k0 = 0; k0 < KDIM; k0 += 64) {
    __syncthreads();                          // LDS reads of prev iter done
    *(ushort8*)&sA[arow][ac8]       = pa0;
    *(ushort8*)&sA[arow + 32][ac8]  = pa1;
    *(ushort8*)&sB[arow][ac8]       = pb0;
    *(ushort8*)&sB[arow + 32][ac8]  = pb1;
    *(ushort8*)&sB[arow + 64][ac8]  = pb2;
    *(ushort8*)&sB[arow + 96][ac8]  = pb3;
    __syncthreads();
    if (k0 + 64 < KDIM) {                     // prefetch next chunk
      pa0 = *(const ushort8*)(Aptr0 + k0 + 64);
      pa1 = *(const ushort8*)(Aptr1 + k0 + 64);
      pb0 = *(const ushort8*)(Bptr + k0 + 64);
      pb1 = *(const ushort8*)(Bptr + k0 + 64 + (size_t)32 * KDIM);
      pb2 = *(const ushort8*)(Bptr + k0 + 64 + (size_t)64 * KDIM);
      pb3 = *(const ushort8*)(Bptr + k0 + 64 + (size_t)96 * KDIM);
    }
#pragma unroll
    for (int ks = 0; ks < 2; ks++) {
      short8 af0 = *(const short8*)&sA[wm + m16][ks * 32 + quad * 8];
      short8 af1 = *(const short8*)&sA[wm + 16 + m16][ks * 32 + quad * 8];
#pragma unroll
      for (int nt = 0; nt < 4; nt++) {
        short8 bfg = *(const short8*)&sB[wn + nt * 16 + m16][ks * 32 + quad * 8];
        acc[0][nt] = __builtin_amdgcn_mfma_f32_16x16x32_bf16(af0, bfg, acc[0][nt], 0, 0, 0);
        acc[1][nt] = __builtin_amdgcn_mfma_f32_16x16x32_bf16(af1, bfg, acc[1][nt], 0, 0, 0);
      }
    }
  }
  // epilogue: C/D col = lane&15 (-> n), row = quad*4 + reg (-> m)
#pragma unroll
  for (int sub = 0; sub < 2; sub++) {
#pragma unroll
    for (int nt = 0; nt < 4; nt++) {
#pragma unroll
      for (int r = 0; r < 4; r++) {
        int row_local = wm + sub * 16 + quad * 4 + r;
        int rg = mt * 64 + row_local;
        if (rg < count) {
          int col = n0 + wn + nt * 16 + m16;
          float v = acc[sub][nt][r];
          if (HASBIAS) v += bf2f(biasAll[e * NDIM + col]);
          if (GELU)    v = 0.5f * v * (1.f + erff(v * 0.70710678118654752f));
          int p = sp[row_local];
          if (OUTF32) outF[(size_t)p * NDIM + col] = v;
          else        outB[(size_t)p * NDIM + col] = f2bf(v);
        }
      }
    }
  }
}

// ---------------- K3: LayerNorm per pair, combine weight folded in ----------
__global__ __launch_bounds__(256) void ln_kernel(
    unsigned short* __restrict__ Hbuf,
    const unsigned short* __restrict__ lnwO, const unsigned short* __restrict__ lnwC,
    const unsigned short* __restrict__ lnbO, const unsigned short* __restrict__ lnbC,
    const int* __restrict__ psel, const float* __restrict__ pw,
    const int* __restrict__ flag)
{
  int p = blockIdx.x;
  int tid = threadIdx.x;
  int e = psel[p];
  int isbf = *flag;
  const unsigned short* lnw = isbf ? lnwO : lnwC;
  const unsigned short* lnb = isbf ? lnbO : lnbC;
  unsigned short* hr = Hbuf + (size_t)p * H_FFN;
  bool act = tid < 192;                       // 192*8 = 1536
  float v[8];
  float s = 0.f, sq = 0.f;
  if (act) {
    ushort8 hv = *(const ushort8*)(hr + tid * 8);
#pragma unroll
    for (int j = 0; j < 8; j++) { v[j] = bf2f(hv[j]); s += v[j]; sq += v[j] * v[j]; }
  }
#pragma unroll
  for (int off = 32; off > 0; off >>= 1) {
    s  += __shfl_down(s, off);
    sq += __shfl_down(sq, off);
  }
  __shared__ float red[8];
  int wave = tid >> 6, lane = tid & 63;
  if (lane == 0) { red[wave * 2] = s; red[wave * 2 + 1] = sq; }
  __syncthreads();
  __shared__ float mv[2];
  if (tid == 0) {
    float S = 0.f, Q = 0.f;
    for (int w = 0; w < 4; w++) { S += red[w * 2]; Q += red[w * 2 + 1]; }
    float mu  = S * (1.f / H_FFN);
    float var = Q * (1.f / H_FFN) - mu * mu;  // biased var = jnp.var
    mv[0] = mu; mv[1] = rsqrtf(var + 1e-5f);
  }
  __syncthreads();
  if (act) {
    float mu = mv[0], rstd = mv[1];
    float w = pw[p];
    ushort8 lw = *(const ushort8*)(lnw + e * H_FFN + tid * 8);
    ushort8 lb = *(const ushort8*)(lnb + e * H_FFN + tid * 8);
    ushort8 o;
#pragma unroll
    for (int j = 0; j < 8; j++)
      o[j] = f2bf(((v[j] - mu) * rstd * bf2f(lw[j]) + bf2f(lb[j])) * w);
    *(ushort8*)(hr + tid * 8) = o;
  }
}

// ---------------- K5: sum 4 pair outputs + weighted fc2 bias ----------------
__global__ __launch_bounds__(256) void combine_kernel(
    const float* __restrict__ Y,
    const unsigned short* __restrict__ b2O, const unsigned short* __restrict__ b2C,
    const int* __restrict__ psel, const float* __restrict__ pw,
    unsigned short* __restrict__ out16, float* __restrict__ out32,
    const int* __restrict__ flag)
{
  int t = blockIdx.x;
  int tid = threadIdx.x;
  if (tid >= 192) return;                     // 192*4 = 768
  int isbf = *flag;
  const unsigned short* b2 = isbf ? b2O : b2C;
  int e1 = psel[t * 4 + 1], e2 = psel[t * 4 + 2], e3 = psel[t * 4 + 3];
  float w1 = pw[t * 4 + 1], w2 = pw[t * 4 + 2], w3 = pw[t * 4 + 3];
  int d = tid * 4;
  const float* Yb = Y + (size_t)t * 4 * D_EMB + d;
  floatx4 y0 = *(const floatx4*)(Yb);
  floatx4 y1 = *(const floatx4*)(Yb + D_EMB);
  floatx4 y2 = *(const floatx4*)(Yb + 2 * D_EMB);
  floatx4 y3 = *(const floatx4*)(Yb + 3 * D_EMB);
  ushort4v b0 = *(const ushort4v*)(b2 + d);
  ushort4v bb1 = *(const ushort4v*)(b2 + e1 * D_EMB + d);
  ushort4v bb2 = *(const ushort4v*)(b2 + e2 * D_EMB + d);
  ushort4v bb3 = *(const ushort4v*)(b2 + e3 * D_EMB + d);
  if (isbf) {
    ushort4v o;
#pragma unroll
    for (int j = 0; j < 4; j++) {
      float a = y0[j] + y1[j] + y2[j] + y3[j] + bf2f(b0[j])
              + w1 * bf2f(bb1[j]) + w2 * bf2f(bb2[j]) + w3 * bf2f(bb3[j]);
      o[j] = f2bf(a);
    }
    *(ushort4v*)(out16 + (size_t)t * D_EMB + d) = o;
  } else {
    floatx4 o;
#pragma unroll
    for (int j = 0; j < 4; j++)
      o[j] = y0[j] + y1[j] + y2[j] + y3[j] + bf2f(b0[j])
           + w1 * bf2f(bb1[j]) + w2 * bf2f(bb2[j]) + w3 * bf2f(bb3[j]);
    *(floatx4*)(out32 + (size_t)t * D_EMB + d) = o;
  }
}

extern "C" void kernel_launch(void* const* d_in, const int* in_sizes, int n_in,
                              void* d_out, int out_size, void* d_ws, size_t ws_size,
                              hipStream_t stream)
{
  (void)in_sizes; (void)n_in; (void)out_size; (void)ws_size;
  char* ws = (char*)d_ws;
  int*   cnt   = (int*)ws;                                 // 16 ints
  int*   plist = (int*)(ws + 256);                         // 16*2048 ints
  int*   psel  = (int*)(ws + 131328);                      // 8192 ints
  float* pw    = (float*)(ws + 164096);                    // 8192 f32
  int*   flag  = (int*)(ws + 196864);
  unsigned short* fc1bC = (unsigned short*)(ws + 197120);  // 24576 bf16
  unsigned short* lnwC  = (unsigned short*)(ws + 246272);
  unsigned short* lnbC  = (unsigned short*)(ws + 295424);
  unsigned short* fc2bC = (unsigned short*)(ws + 344576);  // 12288 bf16
  unsigned short* xC    = (unsigned short*)(ws + 524288);  // 1572864 bf16
  unsigned short* Hbuf  = (unsigned short*)(ws + 3670016); // 8192*1536 bf16
  float*          Ybuf  = (float*)(ws + 28835840);         // 8192*768 f32
  unsigned short* fc1T  = (unsigned short*)(ws + 54001664);// [16][1536][768] bf16
  unsigned short* fc2T  = (unsigned short*)(ws + 91750400);// [16][768][1536] bf16

  hipMemsetAsync(cnt, 0, 64, stream);
  sniff_kernel<<<1, 64, 0, stream>>>((const unsigned int*)d_in[0], flag);

  conv_kernel<<<2048, 256, 0, stream>>>(
      (const float*)d_in[0], (const float*)d_in[4], (const float*)d_in[5],
      (const float*)d_in[6], (const float*)d_in[8],
      xC, fc1bC, lnwC, lnbC, fc2bC, flag);

  transpose_kernel<768, 1536><<<16 * 12 * 24, 256, 0, stream>>>(
      (const unsigned short*)d_in[3], (const float*)d_in[3], flag, fc1T);
  transpose_kernel<1536, 768><<<16 * 24 * 12, 256, 0, stream>>>(
      (const unsigned short*)d_in[7], (const float*)d_in[7], flag, fc2T);

  gate_kernel<<<T_TOK, 64, 0, stream>>>(
      (const unsigned short*)d_in[0], (const float*)d_in[0],
      (const unsigned short*)d_in[1], (const float*)d_in[1],
      (const unsigned short*)d_in[2], (const float*)d_in[2],
      flag, cnt, plist, psel, pw);

  moe_gemm<D_EMB, H_FFN, true, true, true, false>
      <<<NE * 32 * (H_FFN / 128), 256, 0, stream>>>(
      (const unsigned short*)d_in[0], xC, fc1T,
      (const unsigned short*)d_in[4], fc1bC,
      flag, cnt, plist, Hbuf, nullptr);

  ln_kernel<<<NPAIR, 256, 0, stream>>>(
      Hbuf,
      (const unsigned short*)d_in[5], lnwC,
      (const unsigned short*)d_in[6], lnbC,
      psel, pw, flag);

  moe_gemm<H_FFN, D_EMB, false, false, false, true>
      <<<NE * 32 * (D_EMB / 128), 256, 0, stream>>>(
      Hbuf, Hbuf, fc2T,
      nullptr, nullptr,
      flag, cnt, plist, nullptr, Ybuf);

  combine_kernel<<<T_TOK, 256, 0, stream>>>(
      Ybuf,
      (const unsigned short*)d_in[8], fc2bC,
      psel, pw,
      (unsigned short*)d_out, (float*)d_out, flag);
}

// Round 5
// 368.124 us; speedup vs baseline: 2.0795x; 1.1551x over previous
//
#include <hip/hip_runtime.h>
#include <cmath>

#define T_TOK 2048
#define D_EMB 768
#define H_FFN 1536
#define NE    16
#define NPAIR (T_TOK * 4)

typedef __attribute__((ext_vector_type(8))) short          short8;
typedef __attribute__((ext_vector_type(8))) unsigned short ushort8;
typedef __attribute__((ext_vector_type(4))) unsigned short ushort4v;
typedef __attribute__((ext_vector_type(4))) float          floatx4;

__device__ __forceinline__ float bf2f(unsigned short u) {
  union { unsigned int i; float f; } v; v.i = ((unsigned int)u) << 16; return v.f;
}
__device__ __forceinline__ unsigned short f2bf(float f) {
  union { float f; unsigned int i; } v; v.f = f;
  unsigned int r = v.i + 0x7fffu + ((v.i >> 16) & 1u);   // RNE
  return (unsigned short)(r >> 16);
}

// ---------------- K0: dtype sniff (1 = inputs are bf16) ---------------------
__global__ __launch_bounds__(64) void sniff_kernel(
    const unsigned int* __restrict__ x, int* __restrict__ flag)
{
  int lane = threadIdx.x;
  int c = 0;
  for (int i = 0; i < 8; i++) {
    unsigned int w = x[i * 64 + lane];
    unsigned int e = (w >> 7) & 0xFFu;
    c += (e >= 100u && e <= 140u) ? 1 : 0;
  }
  for (int off = 32; off > 0; off >>= 1) c += __shfl_down(c, off);
  if (lane == 0) *flag = (c > 300) ? 1 : 0;
}

// ---------------- K0b: f32 -> bf16 for x + small vectors (f32 mode only) ----
__global__ __launch_bounds__(256) void conv_kernel(
    const float* __restrict__ x, const float* __restrict__ fc1b,
    const float* __restrict__ lnw, const float* __restrict__ lnb,
    const float* __restrict__ fc2b,
    unsigned short* __restrict__ dx, unsigned short* __restrict__ dfc1b,
    unsigned short* __restrict__ dlnw, unsigned short* __restrict__ dlnb,
    unsigned short* __restrict__ dfc2b, const int* __restrict__ flag)
{
  if (*flag) return;
  int g = blockIdx.x * 256 + threadIdx.x;          // grid 2048*256 = 524288
#pragma unroll
  for (int i = 0; i < 3; i++) dx[g + i * 524288] = f2bf(x[g + i * 524288]);
  if (g < 24576) { dfc1b[g] = f2bf(fc1b[g]); dlnw[g] = f2bf(lnw[g]); dlnb[g] = f2bf(lnb[g]); }
  if (g < 12288) dfc2b[g] = f2bf(fc2b[g]);
}

// ---------------- K0c: weight transpose [e][R][C] -> [e][C][R] bf16 ---------
template<int R, int C>
__global__ __launch_bounds__(256) void transpose_kernel(
    const unsigned short* __restrict__ srcB, const float* __restrict__ srcF,
    const int* __restrict__ flag, unsigned short* __restrict__ dst)
{
  __shared__ __align__(16) unsigned short tile[64][72];
  constexpr int RT = R / 64, CT = C / 64;
  int bx  = blockIdx.x;
  int e   = bx / (RT * CT);
  int rem = bx % (RT * CT);
  int rt  = rem / CT, ct = rem % CT;
  int tid = threadIdx.x;
  int r   = tid >> 2;
  int c   = (tid & 3) * 16;
  int xr  = (r & 7) * 8;                       // XOR swizzle per row
  size_t sbase = ((size_t)e * R + rt * 64 + r) * C + ct * 64 + c;
  if (*flag) {
    ushort8 v0 = *(const ushort8*)(srcB + sbase);
    ushort8 v1 = *(const ushort8*)(srcB + sbase + 8);
    *(ushort8*)&tile[r][(c) ^ xr]     = v0;
    *(ushort8*)&tile[r][(c + 8) ^ xr] = v1;
  } else {
    unsigned short tmp[16];
#pragma unroll
    for (int q = 0; q < 4; q++) {
      floatx4 f = *(const floatx4*)(srcF + sbase + q * 4);
#pragma unroll
      for (int j = 0; j < 4; j++) tmp[q * 4 + j] = f2bf(f[j]);
    }
    *(ushort8*)&tile[r][(c) ^ xr]     = *(ushort8*)&tmp[0];
    *(ushort8*)&tile[r][(c + 8) ^ xr] = *(ushort8*)&tmp[8];
  }
  __syncthreads();
  int n  = tid >> 2;
  int k  = (tid & 3) * 16;
  unsigned short outv[16];
#pragma unroll
  for (int j = 0; j < 16; j++) {
    int kr = k + j;
    outv[j] = tile[kr][n ^ ((kr & 7) * 8)];
  }
  size_t dbase = ((size_t)e * C + ct * 64 + n) * R + rt * 64 + k;
  *(ushort8*)(dst + dbase)     = *(ushort8*)&outv[0];
  *(ushort8*)(dst + dbase + 8) = *(ushort8*)&outv[8];
}

// ---------------- K1: gating, wave-parallel, ZERO atomics -------------------
// Writes only psel/pw. List building moved to bucket_kernel.
__global__ __launch_bounds__(64) void gate_kernel(
    const unsigned short* __restrict__ x16, const float* __restrict__ x32,
    const unsigned short* __restrict__ gw16, const float* __restrict__ gw32,
    const unsigned short* __restrict__ gb16, const float* __restrict__ gb32,
    const int* __restrict__ flag,
    int* __restrict__ psel, float* __restrict__ pw)
{
  int t = blockIdx.x;
  int lane = threadIdx.x;
  int isbf = *flag;
  float acc[NE];
#pragma unroll
  for (int e = 0; e < NE; e++) acc[e] = 0.f;
  if (isbf) {
#pragma unroll
    for (int i = 0; i < D_EMB / 64; i++) {
      int d = i * 64 + lane;
      float xv = bf2f(x16[(size_t)t * D_EMB + d]);
      ushort8 g0 = *(const ushort8*)(gw16 + d * NE);
      ushort8 g1 = *(const ushort8*)(gw16 + d * NE + 8);
#pragma unroll
      for (int e = 0; e < 8; e++) acc[e]     += xv * bf2f(g0[e]);
#pragma unroll
      for (int e = 0; e < 8; e++) acc[8 + e] += xv * bf2f(g1[e]);
    }
  } else {
#pragma unroll
    for (int i = 0; i < D_EMB / 64; i++) {
      int d = i * 64 + lane;
      float xv = x32[(size_t)t * D_EMB + d];
#pragma unroll
      for (int q = 0; q < 4; q++) {
        floatx4 g = *(const floatx4*)(gw32 + d * NE + q * 4);
#pragma unroll
        for (int j = 0; j < 4; j++) acc[q * 4 + j] += xv * g[j];
      }
    }
  }
  __shared__ __align__(16) float sacc[64][NE + 1];
#pragma unroll
  for (int e = 0; e < NE; e++) sacc[lane][e] = acc[e];
  __syncthreads();
  // lane handles expert e = lane&15, quarter q = lane>>4
  int e = lane & 15, q = lane >> 4;
  float s = 0.f;
#pragma unroll
  for (int i = 0; i < 16; i++) s += sacc[q * 16 + i][e];
  s += __shfl_xor(s, 16);
  s += __shfl_xor(s, 32);                     // all lanes: full score for e
  float sv = s + (isbf ? bf2f(gb16[e]) : gb32[e]);
  if (e == 0) sv = -1e9f;                     // masked shared-expert logit
  // softmax over the 16-lane expert group
  float m = sv;
#pragma unroll
  for (int off = 8; off > 0; off >>= 1) m = fmaxf(m, __shfl_xor(m, off));
  float pe = expf(sv - m);
  float den = pe;
#pragma unroll
  for (int off = 8; off > 0; off >>= 1) den += __shfl_xor(den, off);
  float pr = pe / den;                        // pr==0 exactly for e==0
  // top-3: butterfly argmax, strict >, lowest index wins ties (= lax.top_k)
  float val = (e == 0) ? -1.f : pr;
  int sel0, sel1, sel2; float sw0, sw1, sw2;
#pragma unroll
  for (int k = 0; k < 3; k++) {
    float bv = val; int bi = e;
#pragma unroll
    for (int off = 8; off > 0; off >>= 1) {
      float ov = __shfl_xor(bv, off);
      int   oi = __shfl_xor(bi, off);
      if (ov > bv || (ov == bv && oi < bi)) { bv = ov; bi = oi; }
    }
    if (k == 0) { sel0 = bi; sw0 = bv; }
    else if (k == 1) { sel1 = bi; sw1 = bv; }
    else { sel2 = bi; sw2 = bv; }
    if (e == bi) val = -1.f;                  // remove winner
  }
  if (lane == 0) {
    psel[t * 4] = 0;    pw[t * 4] = 1.0f;     // shared expert slot
    psel[t * 4 + 1] = sel0; pw[t * 4 + 1] = sw0;
    psel[t * 4 + 2] = sel1; pw[t * 4 + 2] = sw1;
    psel[t * 4 + 3] = sel2; pw[t * 4 + 3] = sw2;
  }
}

// ---------------- K1b: deterministic per-expert compaction (no atomics) -----
// Block e scans psel[0..8191] in order; ordered compaction via ballot+prefix.
__global__ __launch_bounds__(256) void bucket_kernel(
    const int* __restrict__ psel, int* __restrict__ cnt, int* __restrict__ plist)
{
  int e = blockIdx.x;
  int tid = threadIdx.x;
  int wave = tid >> 6, lane = tid & 63;
  __shared__ int wsum[4];
  __shared__ int base;
  if (tid == 0) base = 0;
  __syncthreads();
  for (int c0 = 0; c0 < NPAIR; c0 += 256) {
    bool mt = (psel[c0 + tid] == e);
    unsigned long long mask = __ballot(mt);
    int wcount = __popcll(mask);
    if (lane == 0) wsum[wave] = wcount;
    __syncthreads();
    int wpre = 0;
#pragma unroll
    for (int w = 0; w < 4; w++) if (w < wave) wpre += wsum[w];
    int total = wsum[0] + wsum[1] + wsum[2] + wsum[3];
    if (mt) {
      int off = __popcll(mask & ((1ULL << lane) - 1ULL));
      plist[e * T_TOK + base + wpre + off] = c0 + tid;
    }
    __syncthreads();
    if (tid == 0) base += total;
    __syncthreads();
  }
  if (tid == 0) cnt[e] = base;
}

// ---------------- K2/K4: grouped GEMM, B^T layout, conflict-free LDS --------
// Block: 64 rows x 128 cols, KCH=64. 4 waves as 2x2 -> wave tile 32x64.
template<int KDIM, int NDIM, bool GELU, bool HASBIAS, bool AROWDIV4, bool OUTF32>
__global__ __launch_bounds__(256) void moe_gemm(
    const unsigned short* __restrict__ AO, const unsigned short* __restrict__ AC,
    const unsigned short* __restrict__ BT,       // [e][NDIM][KDIM]
    const unsigned short* __restrict__ biasO, const unsigned short* __restrict__ biasC,
    const int* __restrict__ flag,
    const int* __restrict__ cnt, const int* __restrict__ plist,
    unsigned short* __restrict__ outB, float* __restrict__ outF)
{
  const int NSP = NDIM / 128;
  int bx  = blockIdx.x;
  int e   = bx / (32 * NSP);
  int rem = bx % (32 * NSP);
  int mt  = rem / NSP;
  int ns  = rem % NSP;
  int count = cnt[e];
  if (mt * 64 >= count) return;
  const unsigned short* Abase   = (*flag) ? AO : AC;
  const unsigned short* biasAll = (*flag) ? biasO : biasC;

  __shared__ __align__(16) unsigned short sA[64][72];
  __shared__ __align__(16) unsigned short sB[128][72];
  __shared__ int sp[64];

  int tid = threadIdx.x;
  if (tid < 64) {
    int rg  = mt * 64 + tid;
    int idx = rg < count ? rg : count - 1;    // duplicate last row (pad)
    sp[tid] = plist[e * T_TOK + idx];
  }
  __syncthreads();

  int arow = tid >> 3;                        // 0..31
  int ac8  = (tid & 7) * 8;
  int pr0 = sp[arow], pr1 = sp[arow + 32];
  const unsigned short* Aptr0 = Abase + (size_t)(AROWDIV4 ? (pr0 >> 2) : pr0) * KDIM + ac8;
  const unsigned short* Aptr1 = Abase + (size_t)(AROWDIV4 ? (pr1 >> 2) : pr1) * KDIM + ac8;
  int n0 = ns * 128;
  const unsigned short* Bptr =
      BT + ((size_t)e * NDIM + n0 + arow) * KDIM + ac8;

  int lane = tid & 63;
  int wave = tid >> 6;
  int wm   = (wave >> 1) * 32;
  int wn   = (wave & 1) * 64;
  int m16  = lane & 15;
  int quad = lane >> 4;

  floatx4 acc[2][4];
#pragma unroll
  for (int i = 0; i < 2; i++)
#pragma unroll
    for (int j = 0; j < 4; j++) acc[i][j] = (floatx4){0.f, 0.f, 0.f, 0.f};

  ushort8 pa0 = *(const ushort8*)(Aptr0);
  ushort8 pa1 = *(const ushort8*)(Aptr1);
  ushort8 pb0 = *(const ushort8*)(Bptr);
  ushort8 pb1 = *(const ushort8*)(Bptr + (size_t)32 * KDIM);
  ushort8 pb2 = *(const ushort8*)(Bptr + (size_t)64 * KDIM);
  ushort8 pb3 = *(const ushort8*)(Bptr + (size_t)96 * KDIM);

  for (int k0 = 0; k0 < KDIM; k0 += 64) {
    __syncthreads();                          // LDS reads of prev iter done
    *(ushort8*)&sA[arow][ac8]       = pa0;
    *(ushort8*)&sA[arow + 32][ac8]  = pa1;
    *(ushort8*)&sB[arow][ac8]       = pb0;
    *(ushort8*)&sB[arow + 32][ac8]  = pb1;
    *(ushort8*)&sB[arow + 64][ac8]  = pb2;
    *(ushort8*)&sB[arow + 96][ac8]  = pb3;
    __syncthreads();
    if (k0 + 64 < KDIM) {                     // prefetch next chunk
      pa0 = *(const ushort8*)(Aptr0 + k0 + 64);
      pa1 = *(const ushort8*)(Aptr1 + k0 + 64);
      pb0 = *(const ushort8*)(Bptr + k0 + 64);
      pb1 = *(const ushort8*)(Bptr + k0 + 64 + (size_t)32 * KDIM);
      pb2 = *(const ushort8*)(Bptr + k0 + 64 + (size_t)64 * KDIM);
      pb3 = *(const ushort8*)(Bptr + k0 + 64 + (size_t)96 * KDIM);
    }
#pragma unroll
    for (int ks = 0; ks < 2; ks++) {
      short8 af0 = *(const short8*)&sA[wm + m16][ks * 32 + quad * 8];
      short8 af1 = *(const short8*)&sA[wm + 16 + m16][ks * 32 + quad * 8];
#pragma unroll
      for (int nt = 0; nt < 4; nt++) {
        short8 bfg = *(const short8*)&sB[wn + nt * 16 + m16][ks * 32 + quad * 8];
        acc[0][nt] = __builtin_amdgcn_mfma_f32_16x16x32_bf16(af0, bfg, acc[0][nt], 0, 0, 0);
        acc[1][nt] = __builtin_amdgcn_mfma_f32_16x16x32_bf16(af1, bfg, acc[1][nt], 0, 0, 0);
      }
    }
  }
  // epilogue: C/D col = lane&15 (-> n), row = quad*4 + reg (-> m)
#pragma unroll
  for (int sub = 0; sub < 2; sub++) {
#pragma unroll
    for (int nt = 0; nt < 4; nt++) {
#pragma unroll
      for (int r = 0; r < 4; r++) {
        int row_local = wm + sub * 16 + quad * 4 + r;
        int rg = mt * 64 + row_local;
        if (rg < count) {
          int col = n0 + wn + nt * 16 + m16;
          float v = acc[sub][nt][r];
          if (HASBIAS) v += bf2f(biasAll[e * NDIM + col]);
          if (GELU)    v = 0.5f * v * (1.f + erff(v * 0.70710678118654752f));
          int p = sp[row_local];
          if (OUTF32) outF[(size_t)p * NDIM + col] = v;
          else        outB[(size_t)p * NDIM + col] = f2bf(v);
        }
      }
    }
  }
}

// ---------------- K3: LayerNorm per pair, combine weight folded in ----------
__global__ __launch_bounds__(256) void ln_kernel(
    unsigned short* __restrict__ Hbuf,
    const unsigned short* __restrict__ lnwO, const unsigned short* __restrict__ lnwC,
    const unsigned short* __restrict__ lnbO, const unsigned short* __restrict__ lnbC,
    const int* __restrict__ psel, const float* __restrict__ pw,
    const int* __restrict__ flag)
{
  int p = blockIdx.x;
  int tid = threadIdx.x;
  int e = psel[p];
  int isbf = *flag;
  const unsigned short* lnw = isbf ? lnwO : lnwC;
  const unsigned short* lnb = isbf ? lnbO : lnbC;
  unsigned short* hr = Hbuf + (size_t)p * H_FFN;
  bool act = tid < 192;                       // 192*8 = 1536
  float v[8];
  float s = 0.f, sq = 0.f;
  if (act) {
    ushort8 hv = *(const ushort8*)(hr + tid * 8);
#pragma unroll
    for (int j = 0; j < 8; j++) { v[j] = bf2f(hv[j]); s += v[j]; sq += v[j] * v[j]; }
  }
#pragma unroll
  for (int off = 32; off > 0; off >>= 1) {
    s  += __shfl_down(s, off);
    sq += __shfl_down(sq, off);
  }
  __shared__ float red[8];
  int wave = tid >> 6, lane = tid & 63;
  if (lane == 0) { red[wave * 2] = s; red[wave * 2 + 1] = sq; }
  __syncthreads();
  __shared__ float mv[2];
  if (tid == 0) {
    float S = 0.f, Q = 0.f;
    for (int w = 0; w < 4; w++) { S += red[w * 2]; Q += red[w * 2 + 1]; }
    float mu  = S * (1.f / H_FFN);
    float var = Q * (1.f / H_FFN) - mu * mu;  // biased var = jnp.var
    mv[0] = mu; mv[1] = rsqrtf(var + 1e-5f);
  }
  __syncthreads();
  if (act) {
    float mu = mv[0], rstd = mv[1];
    float w = pw[p];
    ushort8 lw = *(const ushort8*)(lnw + e * H_FFN + tid * 8);
    ushort8 lb = *(const ushort8*)(lnb + e * H_FFN + tid * 8);
    ushort8 o;
#pragma unroll
    for (int j = 0; j < 8; j++)
      o[j] = f2bf(((v[j] - mu) * rstd * bf2f(lw[j]) + bf2f(lb[j])) * w);
    *(ushort8*)(hr + tid * 8) = o;
  }
}

// ---------------- K5: sum 4 pair outputs + weighted fc2 bias ----------------
__global__ __launch_bounds__(256) void combine_kernel(
    const float* __restrict__ Y,
    const unsigned short* __restrict__ b2O, const unsigned short* __restrict__ b2C,
    const int* __restrict__ psel, const float* __restrict__ pw,
    unsigned short* __restrict__ out16, float* __restrict__ out32,
    const int* __restrict__ flag)
{
  int t = blockIdx.x;
  int tid = threadIdx.x;
  if (tid >= 192) return;                     // 192*4 = 768
  int isbf = *flag;
  const unsigned short* b2 = isbf ? b2O : b2C;
  int e1 = psel[t * 4 + 1], e2 = psel[t * 4 + 2], e3 = psel[t * 4 + 3];
  float w1 = pw[t * 4 + 1], w2 = pw[t * 4 + 2], w3 = pw[t * 4 + 3];
  int d = tid * 4;
  const float* Yb = Y + (size_t)t * 4 * D_EMB + d;
  floatx4 y0 = *(const floatx4*)(Yb);
  floatx4 y1 = *(const floatx4*)(Yb + D_EMB);
  floatx4 y2 = *(const floatx4*)(Yb + 2 * D_EMB);
  floatx4 y3 = *(const floatx4*)(Yb + 3 * D_EMB);
  ushort4v b0 = *(const ushort4v*)(b2 + d);
  ushort4v bb1 = *(const ushort4v*)(b2 + e1 * D_EMB + d);
  ushort4v bb2 = *(const ushort4v*)(b2 + e2 * D_EMB + d);
  ushort4v bb3 = *(const ushort4v*)(b2 + e3 * D_EMB + d);
  if (isbf) {
    ushort4v o;
#pragma unroll
    for (int j = 0; j < 4; j++) {
      float a = y0[j] + y1[j] + y2[j] + y3[j] + bf2f(b0[j])
              + w1 * bf2f(bb1[j]) + w2 * bf2f(bb2[j]) + w3 * bf2f(bb3[j]);
      o[j] = f2bf(a);
    }
    *(ushort4v*)(out16 + (size_t)t * D_EMB + d) = o;
  } else {
    floatx4 o;
#pragma unroll
    for (int j = 0; j < 4; j++)
      o[j] = y0[j] + y1[j] + y2[j] + y3[j] + bf2f(b0[j])
           + w1 * bf2f(bb1[j]) + w2 * bf2f(bb2[j]) + w3 * bf2f(bb3[j]);
    *(floatx4*)(out32 + (size_t)t * D_EMB + d) = o;
  }
}

extern "C" void kernel_launch(void* const* d_in, const int* in_sizes, int n_in,
                              void* d_out, int out_size, void* d_ws, size_t ws_size,
                              hipStream_t stream)
{
  (void)in_sizes; (void)n_in; (void)out_size; (void)ws_size;
  char* ws = (char*)d_ws;
  int*   cnt   = (int*)ws;                                 // 16 ints
  int*   plist = (int*)(ws + 256);                         // 16*2048 ints
  int*   psel  = (int*)(ws + 131328);                      // 8192 ints
  float* pw    = (float*)(ws + 164096);                    // 8192 f32
  int*   flag  = (int*)(ws + 196864);
  unsigned short* fc1bC = (unsigned short*)(ws + 197120);  // 24576 bf16
  unsigned short* lnwC  = (unsigned short*)(ws + 246272);
  unsigned short* lnbC  = (unsigned short*)(ws + 295424);
  unsigned short* fc2bC = (unsigned short*)(ws + 344576);  // 12288 bf16
  unsigned short* xC    = (unsigned short*)(ws + 524288);  // 1572864 bf16
  unsigned short* Hbuf  = (unsigned short*)(ws + 3670016); // 8192*1536 bf16
  float*          Ybuf  = (float*)(ws + 28835840);         // 8192*768 f32
  unsigned short* fc1T  = (unsigned short*)(ws + 54001664);// [16][1536][768] bf16
  unsigned short* fc2T  = (unsigned short*)(ws + 91750400);// [16][768][1536] bf16

  sniff_kernel<<<1, 64, 0, stream>>>((const unsigned int*)d_in[0], flag);

  conv_kernel<<<2048, 256, 0, stream>>>(
      (const float*)d_in[0], (const float*)d_in[4], (const float*)d_in[5],
      (const float*)d_in[6], (const float*)d_in[8],
      xC, fc1bC, lnwC, lnbC, fc2bC, flag);

  transpose_kernel<768, 1536><<<16 * 12 * 24, 256, 0, stream>>>(
      (const unsigned short*)d_in[3], (const float*)d_in[3], flag, fc1T);
  transpose_kernel<1536, 768><<<16 * 24 * 12, 256, 0, stream>>>(
      (const unsigned short*)d_in[7], (const float*)d_in[7], flag, fc2T);

  gate_kernel<<<T_TOK, 64, 0, stream>>>(
      (const unsigned short*)d_in[0], (const float*)d_in[0],
      (const unsigned short*)d_in[1], (const float*)d_in[1],
      (const unsigned short*)d_in[2], (const float*)d_in[2],
      flag, psel, pw);

  bucket_kernel<<<NE, 256, 0, stream>>>(psel, cnt, plist);

  moe_gemm<D_EMB, H_FFN, true, true, true, false>
      <<<NE * 32 * (H_FFN / 128), 256, 0, stream>>>(
      (const unsigned short*)d_in[0], xC, fc1T,
      (const unsigned short*)d_in[4], fc1bC,
      flag, cnt, plist, Hbuf, nullptr);

  ln_kernel<<<NPAIR, 256, 0, stream>>>(
      Hbuf,
      (const unsigned short*)d_in[5], lnwC,
      (const unsigned short*)d_in[6], lnbC,
      psel, pw, flag);

  moe_gemm<H_FFN, D_EMB, false, false, false, true>
      <<<NE * 32 * (D_EMB / 128), 256, 0, stream>>>(
      Hbuf, Hbuf, fc2T,
      nullptr, nullptr,
      flag, cnt, plist, nullptr, Ybuf);

  combine_kernel<<<T_TOK, 256, 0, stream>>>(
      Ybuf,
      (const unsigned short*)d_in[8], fc2bC,
      psel, pw,
      (unsigned short*)d_out, (float*)d_out, flag);
}